// Round 4
// baseline (496.513 us; speedup 1.0000x reference)
//
#include <hip/hip_runtime.h>

// ChemResBlock: A=2048 atoms, D=64 depth, F=12 taps.
// out[a,o] = sum_{n,f} conn[a][n*12+f] * Gt[o][n*12+f] + bterm[a,o]
// R4: conn pre-converted ONCE to a tiled bf16 layout
//   connt[atile 16][ks 48][kb 8][row 128][c 64]  (tile = 128 KB, contiguous)
// so the GEMM kernel streams perfectly sequential 16-KB blocks per K-step.
// gt produced in matching tiled layout gtt[ks][kb][o 64][c 64].
// LDS image swizzle (slot = chunk ^ (row&7)) applied on the glds SOURCE side
// (permutation stays within each 128-B line -> still fully coalesced).

#define A_N 2048
#define D_N 64
#define F_N 12
#define K_TOTAL (A_N * F_N)        // 24576
#define NSPLIT 48
#define KSEG (K_TOTAL / NSPLIT)    // 512
#define BK 64
#define NKB (KSEG / BK)            // 8

typedef short short8 __attribute__((ext_vector_type(8)));
typedef float f32x16 __attribute__((ext_vector_type(16)));

#define GLOAD16(ldsp, gp)                                                        \
  __builtin_amdgcn_global_load_lds(                                              \
      (const __attribute__((address_space(1))) void*)(gp),                       \
      (__attribute__((address_space(3))) void*)(ldsp), 16, 0, 0)

// pack two floats to bf16 pair with round-to-nearest-even
__device__ __forceinline__ unsigned pk_bf16(float a, float b) {
  unsigned ua = __float_as_uint(a);
  unsigned ub = __float_as_uint(b);
  ua += 0x7fffu + ((ua >> 16) & 1u);
  ub += 0x7fffu + ((ub >> 16) & 1u);
  return (ua >> 16) | (ub & 0xffff0000u);
}

__device__ __forceinline__ unsigned short bf16_1(float v) {
  unsigned u = __float_as_uint(v);
  u += 0x7fffu + ((u >> 16) & 1u);
  return (unsigned short)(u >> 16);
}

// ---------------- one-time: conn fp32 -> tiled bf16 ----------------
// grid (16, 48). Block handles tile (atile, ks): 128 rows x 512 k.
// Reads: per row a contiguous 2-KB span (wave64 x 32 B). Writes: packed tile.
__global__ void k_conv(const float* __restrict__ conn, unsigned short* __restrict__ connt) {
  int atile = blockIdx.x, ks = blockIdx.y;
  int t = threadIdx.x, lane = t & 63, w = t >> 6;
  unsigned short* tile = connt + (size_t)(atile * 48 + ks) * 65536;
  int kb = lane >> 3, j = lane & 7;
#pragma unroll 4
  for (int p = 0; p < 32; ++p) {
    int row = w * 32 + p;
    const float4* src = (const float4*)(conn + (size_t)(atile * 128 + row) * K_TOTAL +
                                        ks * 512 + lane * 8);
    float4 a = src[0];
    float4 b = src[1];
    uint4 o;
    o.x = pk_bf16(a.x, a.y);
    o.y = pk_bf16(a.z, a.w);
    o.z = pk_bf16(b.x, b.y);
    o.w = pk_bf16(b.z, b.w);
    *(uint4*)(tile + ((kb * 128 + row) * 8 + j) * 8) = o;
  }
}

// ---------------- prep: x (2048x64) -> xt (64x2048) ----------------
__global__ void k_transpose_x(const float* __restrict__ x, float* __restrict__ xt) {
  __shared__ float ld[64][65];
  int m0 = blockIdx.x * 64;
  int t = threadIdx.x;
  int r = t >> 2, cq = (t & 3) * 16;
  const float4* src = (const float4*)(x + (size_t)(m0 + r) * 64 + cq);
#pragma unroll
  for (int i = 0; i < 4; ++i) {
    float4 v = src[i];
    ld[r][cq + i * 4 + 0] = v.x;
    ld[r][cq + i * 4 + 1] = v.y;
    ld[r][cq + i * 4 + 2] = v.z;
    ld[r][cq + i * 4 + 3] = v.w;
  }
  __syncthreads();
  int c = t >> 2, ml0 = (t & 3) * 16;
  float4* dst = (float4*)(xt + (size_t)c * 2048 + m0 + ml0);
#pragma unroll
  for (int i = 0; i < 4; ++i) {
    float4 v;
    v.x = ld[ml0 + i * 4 + 0][c];
    v.y = ld[ml0 + i * 4 + 1][c];
    v.z = ld[ml0 + i * 4 + 2][c];
    v.w = ld[ml0 + i * 4 + 3][c];
    dst[i] = v;
  }
}

// ---------------- prep: bterm_t[o][a] for both filter sets ----------------
__global__ void k_bterm(const float* __restrict__ bond, const float* __restrict__ f0,
                        const float* __restrict__ f1, float* __restrict__ bt0,
                        float* __restrict__ bt1) {
  int a = blockIdx.x * 64 + (threadIdx.x & 63);
  int o = blockIdx.y * 4 + (threadIdx.x >> 6);
  float s0 = 0.f, s1 = 0.f;
#pragma unroll
  for (int f = 0; f < F_N; ++f) {
#pragma unroll
    for (int j = 0; j < 2; ++j) {
      float bv = bond[a * 24 + f * 2 + j];
      s0 += bv * f0[o * 792 + f * 66 + 64 + j];
      s1 += bv * f1[o * 792 + f * 66 + 64 + j];
    }
  }
  bt0[o * 2048 + a] = s0;
  bt1[o * 2048 + a] = s1;
}

// ---------------- per-layer: Gt -> tiled gtt[ks][kb][o][c] ----------------
__global__ void k_g(const float* __restrict__ vt, const float* __restrict__ filt,
                    unsigned short* __restrict__ gtt) {
  __shared__ float W[12][64];
  int o = blockIdx.y;
  int t = threadIdx.x;
  for (int i = t; i < 768; i += 256) W[i >> 6][i & 63] = filt[o * 792 + (i >> 6) * 66 + (i & 63)];
  __syncthreads();
  int n = blockIdx.x * 256 + t;
  float acc[12] = {0.f, 0.f, 0.f, 0.f, 0.f, 0.f, 0.f, 0.f, 0.f, 0.f, 0.f, 0.f};
#pragma unroll 4
  for (int d = 0; d < 64; ++d) {
    float v = vt[d * 2048 + n];
#pragma unroll
    for (int f = 0; f < F_N; ++f) acc[f] += v * W[f][d];
  }
  int kbase = n * 12;
#pragma unroll
  for (int f = 0; f < F_N; ++f) {
    int k = kbase + f;
    int ks = k >> 9, kb = (k >> 6) & 7, c = k & 63;
    gtt[(((size_t)ks * 8 + kb) * 64 + o) * 64 + c] = bf16_1(acc[f]);
  }
}

// ---------------- per-layer: split-K GEMM, sequential-streaming tiles ----------------
// Block (atile, ks): 128 atoms x 64 o, K-chunk 512 as 8 kb-blocks of 16 KB (conn)
// + 8 KB (gt), each staged via glds(16B) from a CONTIGUOUS span, double-buffered.
__launch_bounds__(256, 3)
__global__ void k_big(const unsigned short* __restrict__ connt,
                      const unsigned short* __restrict__ gtt, float* __restrict__ part) {
  __shared__ __align__(16) unsigned short smem[24576];  // 48 KB
  int t = threadIdx.x, lane = t & 63, w = t >> 6;
  int atile = blockIdx.x, ks = blockIdx.y;
  const unsigned short* ct = connt + (size_t)(atile * 48 + ks) * 65536;
  const unsigned short* gs = gtt + (size_t)ks * 32768;

  int rl = lane >> 3, sl = lane & 7;
  int cs = sl ^ rl;  // source chunk feeding this lane's lds slot (swizzle on src side)

  // lane-fixed source offsets within a kb-block (ushort units) + lds bases
  int cSrc[4], gSrc[2];
  unsigned short *cDst[4], *gDst[2];
#pragma unroll
  for (int j = 0; j < 4; ++j) {
    cSrc[j] = (w * 32 + j * 8 + rl) * 64 + cs * 8;
    cDst[j] = smem + (w * 32 + j * 8) * 64;
  }
#pragma unroll
  for (int j = 0; j < 2; ++j) {
    gSrc[j] = (w * 16 + j * 8 + rl) * 64 + cs * 8;
    gDst[j] = smem + 16384 + (w * 16 + j * 8) * 64;
  }

  f32x16 acc0, acc1;
#pragma unroll
  for (int i = 0; i < 16; ++i) { acc0[i] = 0.f; acc1[i] = 0.f; }

  int oh = w >> 1, ah = w & 1;
  int orow = oh * 32 + (lane & 31);
  int arow = ah * 64 + (lane & 31);
  int sw = lane & 7;
  int khalf = lane >> 5;

  // stage kb=0 into buffer 0
#pragma unroll
  for (int j = 0; j < 4; ++j) GLOAD16(cDst[j], ct + cSrc[j]);
#pragma unroll
  for (int j = 0; j < 2; ++j) GLOAD16(gDst[j], gs + gSrc[j]);

  for (int kb = 0; kb < NKB; ++kb) {
    __syncthreads();  // buffer (kb&1) ready
    if (kb + 1 < NKB) {
      int b = (kb + 1) & 1;
      int co = (kb + 1) * 8192, go = (kb + 1) * 4096;
#pragma unroll
      for (int j = 0; j < 4; ++j) GLOAD16(cDst[j] + b * 8192, ct + co + cSrc[j]);
#pragma unroll
      for (int j = 0; j < 2; ++j) GLOAD16(gDst[j] + b * 4096, gs + go + gSrc[j]);
    }
    const unsigned short* cb = smem + (kb & 1) * 8192;
    const unsigned short* gb = smem + 16384 + (kb & 1) * 4096;
#pragma unroll
    for (int kk = 0; kk < 4; ++kk) {
      int c = kk * 2 + khalf;
      int coff = ((c ^ sw) << 3);
      short8 af = *(const short8*)(gb + orow * 64 + coff);
      short8 b0 = *(const short8*)(cb + arow * 64 + coff);
      short8 b1 = *(const short8*)(cb + (arow + 32) * 64 + coff);
      acc0 = __builtin_amdgcn_mfma_f32_32x32x16_bf16(af, b0, acc0, 0, 0, 0);
      acc1 = __builtin_amdgcn_mfma_f32_32x32x16_bf16(af, b1, acc1, 0, 0, 0);
    }
  }

  // D layout (32x32x16): col(atom) = lane&31, row(o) = (reg&3) + 8*(reg>>2) + 4*(lane>>5)
  float* pp = part + (size_t)ks * (64 * 2048);
  int a0 = atile * 128 + ah * 64 + (lane & 31);
  int ob = oh * 32 + 4 * khalf;
#pragma unroll
  for (int rg = 0; rg < 16; ++rg) {
    int o = ob + (rg & 3) + 8 * (rg >> 2);
    pp[o * 2048 + a0] = acc0[rg];
    pp[o * 2048 + a0 + 32] = acc1[rg];
  }
}

// ---------------- per-layer epilogue: sum partials + bterm (+x) + relu ----------------
__global__ void k_reduce(const float* __restrict__ part, const float* __restrict__ bt,
                         const float* __restrict__ xt, float* __restrict__ curt,
                         float* __restrict__ outp, int residual, int final_layer) {
  int idx = blockIdx.x * 256 + threadIdx.x;  // 0 .. 64*2048-1, layout [o][m]
  float s = bt[idx];
#pragma unroll
  for (int sI = 0; sI < NSPLIT; ++sI) s += part[(size_t)sI * (64 * 2048) + idx];
  if (residual) s += xt[idx];
  s = fmaxf(s, 0.f);
  curt[idx] = s;
  if (final_layer) {
    int o = idx >> 11, m = idx & 2047;
    outp[m * 64 + o] = s;
  }
}

extern "C" void kernel_launch(void* const* d_in, const int* in_sizes, int n_in,
                              void* d_out, int out_size, void* d_ws, size_t ws_size,
                              hipStream_t stream) {
  const float* x    = (const float*)d_in[0];  // (2048, 64)
  const float* conn = (const float*)d_in[1];  // (2048, 2048, 12)
  const float* bond = (const float*)d_in[2];  // (2048, 12, 2)
  const float* f0   = (const float*)d_in[3];  // (64, 12, 66)
  const float* f1   = (const float*)d_in[4];
  float* out = (float*)d_out;                 // (2048, 64)

  char* ws = (char*)d_ws;
  float* xt   = (float*)(ws + 0);              // 64x2048 fp32            512 KB
  float* curt = (float*)(ws + 524288);         // 64x2048 fp32            512 KB
  float* bt0  = (float*)(ws + 1048576);        // 64x2048 fp32            512 KB
  float* bt1  = (float*)(ws + 1572864);        // 64x2048 fp32            512 KB
  unsigned short* gtt = (unsigned short*)(ws + 2097152);     // tiled gt    3 MB
  float* part = (float*)(ws + 5242880);        // 48 x 64x2048 fp32       24 MB
  unsigned short* connt = (unsigned short*)(ws + 33554432);  // tiled conn  96 MB
  // total ~128 MB of d_ws used

  k_conv<<<dim3(16, 48), 256, 0, stream>>>(conn, connt);
  k_transpose_x<<<32, 256, 0, stream>>>(x, xt);
  k_bterm<<<dim3(32, 16), 256, 0, stream>>>(bond, f0, f1, bt0, bt1);

  for (int layer = 0; layer < 4; ++layer) {
    const float* filt = (layer < 2) ? f0 : f1;
    const float* bt   = (layer < 2) ? bt0 : bt1;
    const float* vin  = (layer == 0) ? xt : curt;
    k_g<<<dim3(8, 64), 256, 0, stream>>>(vin, filt, gtt);
    k_big<<<dim3(16, NSPLIT), 256, 0, stream>>>(connt, gtt, part);
    k_reduce<<<512, 256, 0, stream>>>(part, bt, xt, curt, out, layer & 1, layer == 3);
  }
}

// Round 5
// 474.847 us; speedup vs baseline: 1.0456x; 1.0456x over previous
//
#include <hip/hip_runtime.h>

// ChemResBlock: A=2048 atoms, D=64 depth, F=12 taps.
// out[a,o] = sum_{n,f} conn[a][n*12+f] * Gt[o][n*12+f] + bterm[a,o]
// R5: layer-1 GEMM (k_big1) reads conn fp32 directly, converts to bf16
// in-register, feeds LDS (swizzled image) AND writes the tiled bf16 copy
//   connt[atile 16][ks 48][kb 8][row 128][c 64]
// for layers 2-4 (k_big, unchanged from R4: glds(16B) + dbuf + xor-swizzle).

#define A_N 2048
#define D_N 64
#define F_N 12
#define K_TOTAL (A_N * F_N)        // 24576
#define NSPLIT 48
#define KSEG (K_TOTAL / NSPLIT)    // 512
#define BK 64
#define NKB (KSEG / BK)            // 8

typedef short short8 __attribute__((ext_vector_type(8)));
typedef float f32x16 __attribute__((ext_vector_type(16)));

#define GLOAD16(ldsp, gp)                                                        \
  __builtin_amdgcn_global_load_lds(                                              \
      (const __attribute__((address_space(1))) void*)(gp),                       \
      (__attribute__((address_space(3))) void*)(ldsp), 16, 0, 0)

// pack two floats to bf16 pair with round-to-nearest-even
__device__ __forceinline__ unsigned pk_bf16(float a, float b) {
  unsigned ua = __float_as_uint(a);
  unsigned ub = __float_as_uint(b);
  ua += 0x7fffu + ((ua >> 16) & 1u);
  ub += 0x7fffu + ((ub >> 16) & 1u);
  return (ua >> 16) | (ub & 0xffff0000u);
}

__device__ __forceinline__ unsigned short bf16_1(float v) {
  unsigned u = __float_as_uint(v);
  u += 0x7fffu + ((u >> 16) & 1u);
  return (unsigned short)(u >> 16);
}

// ---------------- prep: x transpose (blocks 0..31) + bterm (blocks 32..543) ----------------
__global__ void k_prep(const float* __restrict__ x, float* __restrict__ xt,
                       const float* __restrict__ bond, const float* __restrict__ f0,
                       const float* __restrict__ f1, float* __restrict__ bt0,
                       float* __restrict__ bt1) {
  int t = threadIdx.x;
  if (blockIdx.x < 32) {
    __shared__ float ld[64][65];
    int m0 = blockIdx.x * 64;
    int r = t >> 2, cq = (t & 3) * 16;
    const float4* src = (const float4*)(x + (size_t)(m0 + r) * 64 + cq);
#pragma unroll
    for (int i = 0; i < 4; ++i) {
      float4 v = src[i];
      ld[r][cq + i * 4 + 0] = v.x;
      ld[r][cq + i * 4 + 1] = v.y;
      ld[r][cq + i * 4 + 2] = v.z;
      ld[r][cq + i * 4 + 3] = v.w;
    }
    __syncthreads();
    int c = t >> 2, ml0 = (t & 3) * 16;
    float4* dst = (float4*)(xt + (size_t)c * 2048 + m0 + ml0);
#pragma unroll
    for (int i = 0; i < 4; ++i) {
      float4 v;
      v.x = ld[ml0 + i * 4 + 0][c];
      v.y = ld[ml0 + i * 4 + 1][c];
      v.z = ld[ml0 + i * 4 + 2][c];
      v.w = ld[ml0 + i * 4 + 3][c];
      dst[i] = v;
    }
  } else {
    int b = blockIdx.x - 32;           // 0..511
    int a = (b & 31) * 64 + (t & 63);
    int o = (b >> 5) * 4 + (t >> 6);
    float s0 = 0.f, s1 = 0.f;
#pragma unroll
    for (int f = 0; f < F_N; ++f) {
#pragma unroll
      for (int j = 0; j < 2; ++j) {
        float bv = bond[a * 24 + f * 2 + j];
        s0 += bv * f0[o * 792 + f * 66 + 64 + j];
        s1 += bv * f1[o * 792 + f * 66 + 64 + j];
      }
    }
    bt0[o * 2048 + a] = s0;
    bt1[o * 2048 + a] = s1;
  }
}

// ---------------- per-layer: Gt -> tiled gtt[ks][kb][o][c] ----------------
__global__ void k_g(const float* __restrict__ vt, const float* __restrict__ filt,
                    unsigned short* __restrict__ gtt) {
  __shared__ float W[12][64];
  int o = blockIdx.y;
  int t = threadIdx.x;
  for (int i = t; i < 768; i += 256) W[i >> 6][i & 63] = filt[o * 792 + (i >> 6) * 66 + (i & 63)];
  __syncthreads();
  int n = blockIdx.x * 256 + t;
  float acc[12] = {0.f, 0.f, 0.f, 0.f, 0.f, 0.f, 0.f, 0.f, 0.f, 0.f, 0.f, 0.f};
#pragma unroll 4
  for (int d = 0; d < 64; ++d) {
    float v = vt[d * 2048 + n];
#pragma unroll
    for (int f = 0; f < F_N; ++f) acc[f] += v * W[f][d];
  }
  int kbase = n * 12;
#pragma unroll
  for (int f = 0; f < F_N; ++f) {
    int k = kbase + f;
    int ks = k >> 9, kb = (k >> 6) & 7, c = k & 63;
    gtt[(((size_t)ks * 8 + kb) * 64 + o) * 64 + c] = bf16_1(acc[f]);
  }
}

// ---------------- layer 1: GEMM fused with conn fp32->bf16 conversion ----------------
// Block (atile, ks): per kb-block reads 128 rows x 64 fp32 (32 KB) coalesced
// (lane-consecutive 16B chunks: chunk q = s*256 + w*64 + lane; row=q>>4, c16=q&15),
// packs to bf16, ds_writes swizzled image, and stores packed tile to connt.
__launch_bounds__(256, 3)
__global__ void k_big1(const float* __restrict__ conn, const unsigned short* __restrict__ gtt,
                       unsigned short* __restrict__ connt, float* __restrict__ part) {
  __shared__ __align__(16) unsigned short smem[24576];  // conn dbuf 2x16KB? no: 2x8192 sh + gt 2x4096 sh
  int t = threadIdx.x, lane = t & 63, w = t >> 6;
  int atile = blockIdx.x, ks = blockIdx.y;
  const float* cs0 = conn + (size_t)atile * 128 * K_TOTAL + ks * 512;
  unsigned short* tile = connt + (size_t)(atile * 48 + ks) * 65536;
  const unsigned short* gs = gtt + (size_t)ks * 32768;

  int q0 = w * 64 + lane;
  int gOff[8], lOff[8];
#pragma unroll
  for (int s = 0; s < 8; ++s) {
    int q = q0 + s * 256;
    int row = q >> 4, c16 = q & 15, c = c16 >> 1;
    gOff[s] = row * K_TOTAL + c16 * 4;
    lOff[s] = row * 64 + ((c ^ (row & 7)) << 3) + ((c16 & 1) << 2);
  }

  // gt staging (same as k_big)
  int rl = lane >> 3, sl = lane & 7;
  int csz = sl ^ rl;
  int gSrc[2];
  unsigned short* gDst[2];
#pragma unroll
  for (int j = 0; j < 2; ++j) {
    gSrc[j] = (w * 16 + j * 8 + rl) * 64 + csz * 8;
    gDst[j] = smem + 16384 + (w * 16 + j * 8) * 64;
  }

  f32x16 acc0, acc1;
#pragma unroll
  for (int i = 0; i < 16; ++i) { acc0[i] = 0.f; acc1[i] = 0.f; }

  int oh = w >> 1, ah = w & 1;
  int orow = oh * 32 + (lane & 31);
  int arow = ah * 64 + (lane & 31);
  int sw = lane & 7;
  int khalf = lane >> 5;

  float4 rg[8];
#pragma unroll
  for (int s = 0; s < 8; ++s) rg[s] = *(const float4*)(cs0 + gOff[s]);
  GLOAD16(gDst[0], gs + gSrc[0]);
  GLOAD16(gDst[1], gs + gSrc[1]);

  for (int kb = 0; kb < NKB; ++kb) {
    unsigned short* cb = smem + (kb & 1) * 8192;
    uint2* tb = (uint2*)tile + kb * 2048;
#pragma unroll
    for (int s = 0; s < 8; ++s) {
      uint2 p;
      p.x = pk_bf16(rg[s].x, rg[s].y);
      p.y = pk_bf16(rg[s].z, rg[s].w);
      *(uint2*)(cb + lOff[s]) = p;   // ds_write_b64, swizzled image
      tb[q0 + s * 256] = p;          // coalesced 8B/lane tile store
    }
    __syncthreads();  // ds_writes visible; gt glds(kb) drained
    if (kb + 1 < NKB) {
      int b = (kb + 1) & 1;
      GLOAD16(gDst[0] + b * 4096, gs + (kb + 1) * 4096 + gSrc[0]);
      GLOAD16(gDst[1] + b * 4096, gs + (kb + 1) * 4096 + gSrc[1]);
      const float* nsrc = cs0 + (kb + 1) * 64;
#pragma unroll
      for (int s = 0; s < 8; ++s) rg[s] = *(const float4*)(nsrc + gOff[s]);
    }
    const unsigned short* gb = smem + 16384 + (kb & 1) * 4096;
#pragma unroll
    for (int kk = 0; kk < 4; ++kk) {
      int c = kk * 2 + khalf;
      int coff = ((c ^ sw) << 3);
      short8 af = *(const short8*)(gb + orow * 64 + coff);
      short8 b0 = *(const short8*)(cb + arow * 64 + coff);
      short8 b1 = *(const short8*)(cb + (arow + 32) * 64 + coff);
      acc0 = __builtin_amdgcn_mfma_f32_32x32x16_bf16(af, b0, acc0, 0, 0, 0);
      acc1 = __builtin_amdgcn_mfma_f32_32x32x16_bf16(af, b1, acc1, 0, 0, 0);
    }
  }

  float* pp = part + (size_t)ks * (64 * 2048);
  int a0 = atile * 128 + ah * 64 + (lane & 31);
  int ob = oh * 32 + 4 * khalf;
#pragma unroll
  for (int rg2 = 0; rg2 < 16; ++rg2) {
    int o = ob + (rg2 & 3) + 8 * (rg2 >> 2);
    pp[o * 2048 + a0] = acc0[rg2];
    pp[o * 2048 + a0 + 32] = acc1[rg2];
  }
}

// ---------------- layers 2-4: split-K GEMM over tiled bf16 conn (R4 kernel) ----------------
__launch_bounds__(256, 3)
__global__ void k_big(const unsigned short* __restrict__ connt,
                      const unsigned short* __restrict__ gtt, float* __restrict__ part) {
  __shared__ __align__(16) unsigned short smem[24576];  // 48 KB
  int t = threadIdx.x, lane = t & 63, w = t >> 6;
  int atile = blockIdx.x, ks = blockIdx.y;
  const unsigned short* ct = connt + (size_t)(atile * 48 + ks) * 65536;
  const unsigned short* gs = gtt + (size_t)ks * 32768;

  int rl = lane >> 3, sl = lane & 7;
  int cs = sl ^ rl;

  int cSrc[4], gSrc[2];
  unsigned short *cDst[4], *gDst[2];
#pragma unroll
  for (int j = 0; j < 4; ++j) {
    cSrc[j] = (w * 32 + j * 8 + rl) * 64 + cs * 8;
    cDst[j] = smem + (w * 32 + j * 8) * 64;
  }
#pragma unroll
  for (int j = 0; j < 2; ++j) {
    gSrc[j] = (w * 16 + j * 8 + rl) * 64 + cs * 8;
    gDst[j] = smem + 16384 + (w * 16 + j * 8) * 64;
  }

  f32x16 acc0, acc1;
#pragma unroll
  for (int i = 0; i < 16; ++i) { acc0[i] = 0.f; acc1[i] = 0.f; }

  int oh = w >> 1, ah = w & 1;
  int orow = oh * 32 + (lane & 31);
  int arow = ah * 64 + (lane & 31);
  int sw = lane & 7;
  int khalf = lane >> 5;

#pragma unroll
  for (int j = 0; j < 4; ++j) GLOAD16(cDst[j], ct + cSrc[j]);
#pragma unroll
  for (int j = 0; j < 2; ++j) GLOAD16(gDst[j], gs + gSrc[j]);

  for (int kb = 0; kb < NKB; ++kb) {
    __syncthreads();
    if (kb + 1 < NKB) {
      int b = (kb + 1) & 1;
      int co = (kb + 1) * 8192, go = (kb + 1) * 4096;
#pragma unroll
      for (int j = 0; j < 4; ++j) GLOAD16(cDst[j] + b * 8192, ct + co + cSrc[j]);
#pragma unroll
      for (int j = 0; j < 2; ++j) GLOAD16(gDst[j] + b * 4096, gs + go + gSrc[j]);
    }
    const unsigned short* cb = smem + (kb & 1) * 8192;
    const unsigned short* gb = smem + 16384 + (kb & 1) * 4096;
#pragma unroll
    for (int kk = 0; kk < 4; ++kk) {
      int c = kk * 2 + khalf;
      int coff = ((c ^ sw) << 3);
      short8 af = *(const short8*)(gb + orow * 64 + coff);
      short8 b0 = *(const short8*)(cb + arow * 64 + coff);
      short8 b1 = *(const short8*)(cb + (arow + 32) * 64 + coff);
      acc0 = __builtin_amdgcn_mfma_f32_32x32x16_bf16(af, b0, acc0, 0, 0, 0);
      acc1 = __builtin_amdgcn_mfma_f32_32x32x16_bf16(af, b1, acc1, 0, 0, 0);
    }
  }

  float* pp = part + (size_t)ks * (64 * 2048);
  int a0 = atile * 128 + ah * 64 + (lane & 31);
  int ob = oh * 32 + 4 * khalf;
#pragma unroll
  for (int rg = 0; rg < 16; ++rg) {
    int o = ob + (rg & 3) + 8 * (rg >> 2);
    pp[o * 2048 + a0] = acc0[rg];
    pp[o * 2048 + a0 + 32] = acc1[rg];
  }
}

// ---------------- per-layer epilogue: sum partials + bterm (+x) + relu ----------------
__global__ void k_reduce(const float* __restrict__ part, const float* __restrict__ bt,
                         const float* __restrict__ xt, float* __restrict__ curt,
                         float* __restrict__ outp, int residual, int final_layer) {
  int idx = blockIdx.x * 256 + threadIdx.x;  // 0 .. 64*2048-1, layout [o][m]
  float s = bt[idx];
#pragma unroll
  for (int sI = 0; sI < NSPLIT; ++sI) s += part[(size_t)sI * (64 * 2048) + idx];
  if (residual) s += xt[idx];
  s = fmaxf(s, 0.f);
  curt[idx] = s;
  if (final_layer) {
    int o = idx >> 11, m = idx & 2047;
    outp[m * 64 + o] = s;
  }
}

extern "C" void kernel_launch(void* const* d_in, const int* in_sizes, int n_in,
                              void* d_out, int out_size, void* d_ws, size_t ws_size,
                              hipStream_t stream) {
  const float* x    = (const float*)d_in[0];  // (2048, 64)
  const float* conn = (const float*)d_in[1];  // (2048, 2048, 12)
  const float* bond = (const float*)d_in[2];  // (2048, 12, 2)
  const float* f0   = (const float*)d_in[3];  // (64, 12, 66)
  const float* f1   = (const float*)d_in[4];
  float* out = (float*)d_out;                 // (2048, 64)

  char* ws = (char*)d_ws;
  float* xt   = (float*)(ws + 0);              // 64x2048 fp32            512 KB
  float* curt = (float*)(ws + 524288);         // 64x2048 fp32            512 KB
  float* bt0  = (float*)(ws + 1048576);        // 64x2048 fp32            512 KB
  float* bt1  = (float*)(ws + 1572864);        // 64x2048 fp32            512 KB
  unsigned short* gtt = (unsigned short*)(ws + 2097152);     // tiled gt    3 MB
  float* part = (float*)(ws + 5242880);        // 48 x 64x2048 fp32       24 MB
  unsigned short* connt = (unsigned short*)(ws + 33554432);  // tiled conn  96 MB
  // total ~128 MB of d_ws used

  k_prep<<<544, 256, 0, stream>>>(x, xt, bond, f0, f1, bt0, bt1);

  for (int layer = 0; layer < 4; ++layer) {
    const float* filt = (layer < 2) ? f0 : f1;
    const float* bt   = (layer < 2) ? bt0 : bt1;
    const float* vin  = (layer == 0) ? xt : curt;
    k_g<<<dim3(8, 64), 256, 0, stream>>>(vin, filt, gtt);
    if (layer == 0)
      k_big1<<<dim3(16, NSPLIT), 256, 0, stream>>>(conn, gtt, connt, part);
    else
      k_big<<<dim3(16, NSPLIT), 256, 0, stream>>>(connt, gtt, part);
    k_reduce<<<512, 256, 0, stream>>>(part, bt, xt, curt, out, layer & 1, layer == 3);
  }
}

// Round 6
// 472.953 us; speedup vs baseline: 1.0498x; 1.0040x over previous
//
#include <hip/hip_runtime.h>

// ChemResBlock: A=2048 atoms, D=64 depth, F=12 taps.
// out[a,o] = sum_{n,f} conn[a][n*12+f] * Gt[o][n*12+f] + bterm[a,o]
// R6: NSPLIT 48->32 (halves split-K partial traffic), float4 k_reduce.
// Layer-1 GEMM (k_big1) reads conn fp32 directly, converts to bf16 in-register,
// feeds LDS (swizzled image) AND writes tiled bf16 copy
//   connt[atile 16][ks 32][kb 12][row 128][c 64]
// for layers 2-4 (k_big: glds(16B) + dbuf + xor-swizzle, verified R4 structure).

#define A_N 2048
#define D_N 64
#define F_N 12
#define K_TOTAL (A_N * F_N)        // 24576
#define NSPLIT 32
#define KSEG (K_TOTAL / NSPLIT)    // 768
#define BK 64
#define NKB (KSEG / BK)            // 12

typedef short short8 __attribute__((ext_vector_type(8)));
typedef float f32x16 __attribute__((ext_vector_type(16)));

#define GLOAD16(ldsp, gp)                                                        \
  __builtin_amdgcn_global_load_lds(                                              \
      (const __attribute__((address_space(1))) void*)(gp),                       \
      (__attribute__((address_space(3))) void*)(ldsp), 16, 0, 0)

// pack two floats to bf16 pair with round-to-nearest-even
__device__ __forceinline__ unsigned pk_bf16(float a, float b) {
  unsigned ua = __float_as_uint(a);
  unsigned ub = __float_as_uint(b);
  ua += 0x7fffu + ((ua >> 16) & 1u);
  ub += 0x7fffu + ((ub >> 16) & 1u);
  return (ua >> 16) | (ub & 0xffff0000u);
}

__device__ __forceinline__ unsigned short bf16_1(float v) {
  unsigned u = __float_as_uint(v);
  u += 0x7fffu + ((u >> 16) & 1u);
  return (unsigned short)(u >> 16);
}

// ---------------- prep: x transpose (blocks 0..31) + bterm (blocks 32..543) ----------------
__global__ void k_prep(const float* __restrict__ x, float* __restrict__ xt,
                       const float* __restrict__ bond, const float* __restrict__ f0,
                       const float* __restrict__ f1, float* __restrict__ bt0,
                       float* __restrict__ bt1) {
  int t = threadIdx.x;
  if (blockIdx.x < 32) {
    __shared__ float ld[64][65];
    int m0 = blockIdx.x * 64;
    int r = t >> 2, cq = (t & 3) * 16;
    const float4* src = (const float4*)(x + (size_t)(m0 + r) * 64 + cq);
#pragma unroll
    for (int i = 0; i < 4; ++i) {
      float4 v = src[i];
      ld[r][cq + i * 4 + 0] = v.x;
      ld[r][cq + i * 4 + 1] = v.y;
      ld[r][cq + i * 4 + 2] = v.z;
      ld[r][cq + i * 4 + 3] = v.w;
    }
    __syncthreads();
    int c = t >> 2, ml0 = (t & 3) * 16;
    float4* dst = (float4*)(xt + (size_t)c * 2048 + m0 + ml0);
#pragma unroll
    for (int i = 0; i < 4; ++i) {
      float4 v;
      v.x = ld[ml0 + i * 4 + 0][c];
      v.y = ld[ml0 + i * 4 + 1][c];
      v.z = ld[ml0 + i * 4 + 2][c];
      v.w = ld[ml0 + i * 4 + 3][c];
      dst[i] = v;
    }
  } else {
    int b = blockIdx.x - 32;           // 0..511
    int a = (b & 31) * 64 + (t & 63);
    int o = (b >> 5) * 4 + (t >> 6);
    float s0 = 0.f, s1 = 0.f;
#pragma unroll
    for (int f = 0; f < F_N; ++f) {
#pragma unroll
      for (int j = 0; j < 2; ++j) {
        float bv = bond[a * 24 + f * 2 + j];
        s0 += bv * f0[o * 792 + f * 66 + 64 + j];
        s1 += bv * f1[o * 792 + f * 66 + 64 + j];
      }
    }
    bt0[o * 2048 + a] = s0;
    bt1[o * 2048 + a] = s1;
  }
}

// ---------------- per-layer: Gt -> tiled gtt[ks][kb][o][c] = [q][o][c] ----------------
__global__ void k_g(const float* __restrict__ vt, const float* __restrict__ filt,
                    unsigned short* __restrict__ gtt) {
  __shared__ float W[12][64];
  int o = blockIdx.y;
  int t = threadIdx.x;
  for (int i = t; i < 768; i += 256) W[i >> 6][i & 63] = filt[o * 792 + (i >> 6) * 66 + (i & 63)];
  __syncthreads();
  int n = blockIdx.x * 256 + t;
  float acc[12] = {0.f, 0.f, 0.f, 0.f, 0.f, 0.f, 0.f, 0.f, 0.f, 0.f, 0.f, 0.f};
#pragma unroll 4
  for (int d = 0; d < 64; ++d) {
    float v = vt[d * 2048 + n];
#pragma unroll
    for (int f = 0; f < F_N; ++f) acc[f] += v * W[f][d];
  }
  int kbase = n * 12;
#pragma unroll
  for (int f = 0; f < F_N; ++f) {
    int k = kbase + f;
    int q = k >> 6, c = k & 63;       // q = ks*12+kb, layout [q][o][c]
    gtt[(size_t)q * 4096 + o * 64 + c] = bf16_1(acc[f]);
  }
}

// ---------------- layer 1: GEMM fused with conn fp32->bf16 conversion ----------------
// Block (atile, ks): per kb-block reads 128 rows x 64 fp32 (32 KB) coalesced,
// packs to bf16, ds_writes swizzled image, stores packed tile to connt.
__launch_bounds__(256, 3)
__global__ void k_big1(const float* __restrict__ conn, const unsigned short* __restrict__ gtt,
                       unsigned short* __restrict__ connt, float* __restrict__ part) {
  __shared__ __align__(16) unsigned short smem[24576];  // 2x8K conn sh + 2x4K gt sh (x2B)
  int t = threadIdx.x, lane = t & 63, w = t >> 6;
  int atile = blockIdx.x, ks = blockIdx.y;
  const float* cs0 = conn + (size_t)atile * 128 * K_TOTAL + ks * KSEG;
  unsigned short* tile = connt + (size_t)(atile * NSPLIT + ks) * (NKB * 8192);
  const unsigned short* gs = gtt + (size_t)ks * (NKB * 4096);

  int q0 = w * 64 + lane;
  int gOff[8], lOff[8];
#pragma unroll
  for (int s = 0; s < 8; ++s) {
    int q = q0 + s * 256;
    int row = q >> 4, c16 = q & 15, c = c16 >> 1;
    gOff[s] = row * K_TOTAL + c16 * 4;
    lOff[s] = row * 64 + ((c ^ (row & 7)) << 3) + ((c16 & 1) << 2);
  }

  // gt staging (same as k_big)
  int rl = lane >> 3, sl = lane & 7;
  int csz = sl ^ rl;
  int gSrc[2];
  unsigned short* gDst[2];
#pragma unroll
  for (int j = 0; j < 2; ++j) {
    gSrc[j] = (w * 16 + j * 8 + rl) * 64 + csz * 8;
    gDst[j] = smem + 16384 + (w * 16 + j * 8) * 64;
  }

  f32x16 acc0, acc1;
#pragma unroll
  for (int i = 0; i < 16; ++i) { acc0[i] = 0.f; acc1[i] = 0.f; }

  int oh = w >> 1, ah = w & 1;
  int orow = oh * 32 + (lane & 31);
  int arow = ah * 64 + (lane & 31);
  int sw = lane & 7;
  int khalf = lane >> 5;

  float4 rg[8];
#pragma unroll
  for (int s = 0; s < 8; ++s) rg[s] = *(const float4*)(cs0 + gOff[s]);
  GLOAD16(gDst[0], gs + gSrc[0]);
  GLOAD16(gDst[1], gs + gSrc[1]);

  for (int kb = 0; kb < NKB; ++kb) {
    unsigned short* cb = smem + (kb & 1) * 8192;
    uint2* tb = (uint2*)tile + kb * 2048;
#pragma unroll
    for (int s = 0; s < 8; ++s) {
      uint2 p;
      p.x = pk_bf16(rg[s].x, rg[s].y);
      p.y = pk_bf16(rg[s].z, rg[s].w);
      *(uint2*)(cb + lOff[s]) = p;   // ds_write_b64, swizzled image
      tb[q0 + s * 256] = p;          // coalesced 8B/lane tile store
    }
    __syncthreads();  // ds_writes visible; gt glds(kb) drained
    if (kb + 1 < NKB) {
      int b = (kb + 1) & 1;
      GLOAD16(gDst[0] + b * 4096, gs + (kb + 1) * 4096 + gSrc[0]);
      GLOAD16(gDst[1] + b * 4096, gs + (kb + 1) * 4096 + gSrc[1]);
      const float* nsrc = cs0 + (kb + 1) * 64;
#pragma unroll
      for (int s = 0; s < 8; ++s) rg[s] = *(const float4*)(nsrc + gOff[s]);
    }
    const unsigned short* gb = smem + 16384 + (kb & 1) * 4096;
#pragma unroll
    for (int kk = 0; kk < 4; ++kk) {
      int c = kk * 2 + khalf;
      int coff = ((c ^ sw) << 3);
      short8 af = *(const short8*)(gb + orow * 64 + coff);
      short8 b0 = *(const short8*)(cb + arow * 64 + coff);
      short8 b1 = *(const short8*)(cb + (arow + 32) * 64 + coff);
      acc0 = __builtin_amdgcn_mfma_f32_32x32x16_bf16(af, b0, acc0, 0, 0, 0);
      acc1 = __builtin_amdgcn_mfma_f32_32x32x16_bf16(af, b1, acc1, 0, 0, 0);
    }
  }

  float* pp = part + (size_t)ks * (64 * 2048);
  int a0 = atile * 128 + ah * 64 + (lane & 31);
  int ob = oh * 32 + 4 * khalf;
#pragma unroll
  for (int rg2 = 0; rg2 < 16; ++rg2) {
    int o = ob + (rg2 & 3) + 8 * (rg2 >> 2);
    pp[o * 2048 + a0] = acc0[rg2];
    pp[o * 2048 + a0 + 32] = acc1[rg2];
  }
}

// ---------------- layers 2-4: split-K GEMM over tiled bf16 conn ----------------
__launch_bounds__(256, 3)
__global__ void k_big(const unsigned short* __restrict__ connt,
                      const unsigned short* __restrict__ gtt, float* __restrict__ part) {
  __shared__ __align__(16) unsigned short smem[24576];  // 48 KB
  int t = threadIdx.x, lane = t & 63, w = t >> 6;
  int atile = blockIdx.x, ks = blockIdx.y;
  const unsigned short* ct = connt + (size_t)(atile * NSPLIT + ks) * (NKB * 8192);
  const unsigned short* gs = gtt + (size_t)ks * (NKB * 4096);

  int rl = lane >> 3, sl = lane & 7;
  int cs = sl ^ rl;

  int cSrc[4], gSrc[2];
  unsigned short *cDst[4], *gDst[2];
#pragma unroll
  for (int j = 0; j < 4; ++j) {
    cSrc[j] = (w * 32 + j * 8 + rl) * 64 + cs * 8;
    cDst[j] = smem + (w * 32 + j * 8) * 64;
  }
#pragma unroll
  for (int j = 0; j < 2; ++j) {
    gSrc[j] = (w * 16 + j * 8 + rl) * 64 + cs * 8;
    gDst[j] = smem + 16384 + (w * 16 + j * 8) * 64;
  }

  f32x16 acc0, acc1;
#pragma unroll
  for (int i = 0; i < 16; ++i) { acc0[i] = 0.f; acc1[i] = 0.f; }

  int oh = w >> 1, ah = w & 1;
  int orow = oh * 32 + (lane & 31);
  int arow = ah * 64 + (lane & 31);
  int sw = lane & 7;
  int khalf = lane >> 5;

#pragma unroll
  for (int j = 0; j < 4; ++j) GLOAD16(cDst[j], ct + cSrc[j]);
#pragma unroll
  for (int j = 0; j < 2; ++j) GLOAD16(gDst[j], gs + gSrc[j]);

  for (int kb = 0; kb < NKB; ++kb) {
    __syncthreads();
    if (kb + 1 < NKB) {
      int b = (kb + 1) & 1;
      int co = (kb + 1) * 8192, go = (kb + 1) * 4096;
#pragma unroll
      for (int j = 0; j < 4; ++j) GLOAD16(cDst[j] + b * 8192, ct + co + cSrc[j]);
#pragma unroll
      for (int j = 0; j < 2; ++j) GLOAD16(gDst[j] + b * 4096, gs + go + gSrc[j]);
    }
    const unsigned short* cb = smem + (kb & 1) * 8192;
    const unsigned short* gb = smem + 16384 + (kb & 1) * 4096;
#pragma unroll
    for (int kk = 0; kk < 4; ++kk) {
      int c = kk * 2 + khalf;
      int coff = ((c ^ sw) << 3);
      short8 af = *(const short8*)(gb + orow * 64 + coff);
      short8 b0 = *(const short8*)(cb + arow * 64 + coff);
      short8 b1 = *(const short8*)(cb + (arow + 32) * 64 + coff);
      acc0 = __builtin_amdgcn_mfma_f32_32x32x16_bf16(af, b0, acc0, 0, 0, 0);
      acc1 = __builtin_amdgcn_mfma_f32_32x32x16_bf16(af, b1, acc1, 0, 0, 0);
    }
  }

  float* pp = part + (size_t)ks * (64 * 2048);
  int a0 = atile * 128 + ah * 64 + (lane & 31);
  int ob = oh * 32 + 4 * khalf;
#pragma unroll
  for (int rg = 0; rg < 16; ++rg) {
    int o = ob + (rg & 3) + 8 * (rg >> 2);
    pp[o * 2048 + a0] = acc0[rg];
    pp[o * 2048 + a0 + 32] = acc1[rg];
  }
}

// ---------------- per-layer epilogue: sum partials + bterm (+x) + relu (float4) ----------------
__global__ void k_reduce(const float* __restrict__ part, const float* __restrict__ bt,
                         const float* __restrict__ xt, float* __restrict__ curt,
                         float* __restrict__ outp, int residual, int final_layer) {
  int i4 = blockIdx.x * 256 + threadIdx.x;  // float4 index, 0..32767; layout [o][m]
  float4 s = ((const float4*)bt)[i4];
#pragma unroll
  for (int sI = 0; sI < NSPLIT; ++sI) {
    float4 p = ((const float4*)part)[(size_t)sI * 32768 + i4];
    s.x += p.x; s.y += p.y; s.z += p.z; s.w += p.w;
  }
  if (residual) {
    float4 r = ((const float4*)xt)[i4];
    s.x += r.x; s.y += r.y; s.z += r.z; s.w += r.w;
  }
  s.x = fmaxf(s.x, 0.f); s.y = fmaxf(s.y, 0.f);
  s.z = fmaxf(s.z, 0.f); s.w = fmaxf(s.w, 0.f);
  ((float4*)curt)[i4] = s;
  if (final_layer) {
    int idx = i4 * 4;
    int o = idx >> 11, m = idx & 2047;
    outp[(m + 0) * 64 + o] = s.x;
    outp[(m + 1) * 64 + o] = s.y;
    outp[(m + 2) * 64 + o] = s.z;
    outp[(m + 3) * 64 + o] = s.w;
  }
}

extern "C" void kernel_launch(void* const* d_in, const int* in_sizes, int n_in,
                              void* d_out, int out_size, void* d_ws, size_t ws_size,
                              hipStream_t stream) {
  const float* x    = (const float*)d_in[0];  // (2048, 64)
  const float* conn = (const float*)d_in[1];  // (2048, 2048, 12)
  const float* bond = (const float*)d_in[2];  // (2048, 12, 2)
  const float* f0   = (const float*)d_in[3];  // (64, 12, 66)
  const float* f1   = (const float*)d_in[4];
  float* out = (float*)d_out;                 // (2048, 64)

  char* ws = (char*)d_ws;
  float* xt   = (float*)(ws + 0);              // 64x2048 fp32            512 KB
  float* curt = (float*)(ws + 524288);         // 64x2048 fp32            512 KB
  float* bt0  = (float*)(ws + 1048576);        // 64x2048 fp32            512 KB
  float* bt1  = (float*)(ws + 1572864);        // 64x2048 fp32            512 KB
  unsigned short* gtt = (unsigned short*)(ws + 2097152);     // tiled gt    3 MB
  float* part = (float*)(ws + 5242880);        // 32 x 64x2048 fp32       16 MB
  unsigned short* connt = (unsigned short*)(ws + 33554432);  // tiled conn  96 MB
  // total ~128 MB of d_ws used

  k_prep<<<544, 256, 0, stream>>>(x, xt, bond, f0, f1, bt0, bt1);

  for (int layer = 0; layer < 4; ++layer) {
    const float* filt = (layer < 2) ? f0 : f1;
    const float* bt   = (layer < 2) ? bt0 : bt1;
    const float* vin  = (layer == 0) ? xt : curt;
    k_g<<<dim3(8, 64), 256, 0, stream>>>(vin, filt, gtt);
    if (layer == 0)
      k_big1<<<dim3(16, NSPLIT), 256, 0, stream>>>(conn, gtt, connt, part);
    else
      k_big<<<dim3(16, NSPLIT), 256, 0, stream>>>(connt, gtt, part);
    k_reduce<<<128, 256, 0, stream>>>(part, bt, xt, curt, out, layer & 1, layer == 3);
  }
}